// Round 1
// baseline (778.725 us; speedup 1.0000x reference)
//
#include <hip/hip_runtime.h>
#include <math.h>

// ---------------------------------------------------------------------------
// WEGAT: 3x edge-weighted GAT conv + mean pool + linear head.
// Decomposition: logit[e] = ai[dst] + aj[src] + ae[e]  (att dot split).
// CSR-by-dst built per launch -> atomic-free softmax + aggregation,
// one wave (64 lanes) per destination node.
// ---------------------------------------------------------------------------

__global__ __launch_bounds__(256) void zero_kernel(int* cnt, float* pool, int n, int npool) {
    int i = blockIdx.x * blockDim.x + threadIdx.x;
    if (i < n) cnt[i] = 0;
    if (i < npool) pool[i] = 0.f;
}

__global__ __launch_bounds__(256) void hist_kernel(const int* __restrict__ dst, int* cnt, int E) {
    int e = blockIdx.x * blockDim.x + threadIdx.x;
    if (e < E) atomicAdd(&cnt[dst[e]], 1);
}

// Single-block exclusive scan over N counts (N ~ 50000). 1024 threads,
// each handles a contiguous chunk; Hillis-Steele over the 1024 chunk sums.
__global__ __launch_bounds__(1024) void scan_kernel(const int* __restrict__ cnt,
                                                    int* rowptr, int* cursor, int n) {
    __shared__ int sums[1024];
    int t = threadIdx.x;
    int CH = (n + 1023) >> 10;
    int s0 = t * CH;
    int s1 = min(n, s0 + CH);
    int local = 0;
    for (int i = s0; i < s1; i++) local += cnt[i];
    sums[t] = local;
    __syncthreads();
    for (int off = 1; off < 1024; off <<= 1) {
        int v = (t >= off) ? sums[t - off] : 0;
        __syncthreads();
        sums[t] += v;
        __syncthreads();
    }
    int run = (t == 0) ? 0 : sums[t - 1];
    for (int i = s0; i < s1; i++) {
        rowptr[i] = run;
        cursor[i] = run;
        run += cnt[i];
    }
    if (t == 1023) rowptr[n] = sums[1023];
}

__global__ __launch_bounds__(256) void scatter_kernel(const int* __restrict__ src,
                                                      const int* __restrict__ dst,
                                                      int* cursor, int* eid, int* esrc, int E) {
    int e = blockIdx.x * blockDim.x + threadIdx.x;
    if (e >= E) return;
    int d = dst[e];
    int pos = atomicAdd(&cursor[d], 1);
    eid[pos] = e;
    esrc[pos] = src[e];
}

// xn = xin @ Wn + bn ; ai = xn . att[0:32] ; aj = xn . att[32:64]
// 32 lanes per node (h = lane&31).
template <int IN>
__global__ __launch_bounds__(256) void node_linear(const float* __restrict__ xin,
                                                   const float* __restrict__ Wn,
                                                   const float* __restrict__ bn,
                                                   const float* __restrict__ att,
                                                   float* __restrict__ xn,
                                                   float* __restrict__ ai,
                                                   float* __restrict__ aj, int n) {
    int t = blockIdx.x * blockDim.x + threadIdx.x;
    int node = t >> 5;
    int h = t & 31;
    if (node >= n) return;
    float acc = bn[h];
#pragma unroll
    for (int k = 0; k < IN; k++) {
        acc = fmaf(xin[node * IN + k], Wn[k * 32 + h], acc);
    }
    xn[node * 32 + h] = acc;
    float pi = acc * att[h];
    float pj = acc * att[32 + h];
#pragma unroll
    for (int off = 16; off > 0; off >>= 1) {
        pi += __shfl_xor(pi, off);
        pj += __shfl_xor(pj, off);
    }
    if (h == 0) {
        ai[node] = pi;
        aj[node] = pj;
    }
}

// eout = ein @ We + be (8x8) ; ae = eout . atte. In-place safe (row-wise).
__global__ __launch_bounds__(256) void edge_linear(const float* ein,
                                                   const float* __restrict__ We,
                                                   const float* __restrict__ be,
                                                   const float* __restrict__ atte,
                                                   float* eout, float* __restrict__ ae,
                                                   int E, int store) {
    int e = blockIdx.x * blockDim.x + threadIdx.x;
    if (e >= E) return;
    const float4* p = (const float4*)(ein + (size_t)e * 8);
    float4 x0 = p[0], x1 = p[1];
    float in[8] = {x0.x, x0.y, x0.z, x0.w, x1.x, x1.y, x1.z, x1.w};
    float o[8];
    float dot = 0.f;
#pragma unroll
    for (int j = 0; j < 8; j++) {
        float a = be[j];
#pragma unroll
        for (int k = 0; k < 8; k++) a = fmaf(in[k], We[k * 8 + j], a);
        o[j] = a;
        dot = fmaf(a, atte[j], dot);
    }
    ae[e] = dot;
    if (store) {
        float4* q = (float4*)(eout + (size_t)e * 8);
        q[0] = make_float4(o[0], o[1], o[2], o[3]);
        q[1] = make_float4(o[4], o[5], o[6], o[7]);
    }
}

// One wave per dst node. Phase 1: wave-max of leaky_relu(logit).
// Phase 2: per-lane exp, then 2 half-waves (h = lane&31) accumulate
// sum_e p_e * xn[src_e][h] via shuffle broadcast. Normalize, optional relu.
__global__ __launch_bounds__(256) void gat_aggregate(const float* __restrict__ xn,
                                                     const float* __restrict__ ai,
                                                     const float* __restrict__ aj,
                                                     const float* __restrict__ ae,
                                                     const int* __restrict__ rowptr,
                                                     const int* __restrict__ eid,
                                                     const int* __restrict__ esrc,
                                                     float* __restrict__ xout,
                                                     int n, int relu_out) {
    int wave = (blockIdx.x * blockDim.x + threadIdx.x) >> 6;
    int lane = threadIdx.x & 63;
    if (wave >= n) return;
    int node = wave;
    int row = rowptr[node];
    int deg = rowptr[node + 1] - row;
    int h = lane & 31;
    if (deg == 0) {
        if (lane < 32) xout[node * 32 + h] = 0.f;
        return;
    }
    float a_i = ai[node];

    // phase 1: max logit
    float mx = -INFINITY;
    for (int k = lane; k < deg; k += 64) {
        float lg = a_i + aj[esrc[row + k]] + ae[eid[row + k]];
        lg = (lg >= 0.f) ? lg : 0.2f * lg;
        mx = fmaxf(mx, lg);
    }
#pragma unroll
    for (int off = 32; off > 0; off >>= 1) mx = fmaxf(mx, __shfl_xor(mx, off));

    // phase 2: exp + weighted gather-accumulate
    float acc = 0.f, psum = 0.f;
    int half = lane >> 5;
    for (int base = 0; base < deg; base += 64) {
        int k = base + lane;
        float p = 0.f;
        int s = 0;
        if (k < deg) {
            int e = eid[row + k];
            s = esrc[row + k];
            float lg = a_i + aj[s] + ae[e];
            lg = (lg >= 0.f) ? lg : 0.2f * lg;
            p = expf(lg - mx);
        }
        psum += p;
        int csize = min(64, deg - base);
        for (int j = half; j < csize; j += 2) {
            float pj = __shfl(p, j);
            int sj = __shfl(s, j);
            acc = fmaf(pj, xn[sj * 32 + h], acc);
        }
    }
#pragma unroll
    for (int off = 32; off > 0; off >>= 1) psum += __shfl_xor(psum, off);
    acc += __shfl_xor(acc, 32);

    float o = acc / (psum + 1e-16f);
    if (relu_out) o = fmaxf(o, 0.f);
    if (lane < 32) xout[node * 32 + h] = o;
}

// Sorted-batch running-flush partial pooling: few atomics per thread.
__global__ __launch_bounds__(256) void pool_kernel(const float* __restrict__ x3,
                                                   const int* __restrict__ batch,
                                                   float* pool, int n) {
    int h = threadIdx.x & 31;
    int rowl = threadIdx.x >> 5;  // 0..7
    int per = (n + gridDim.x - 1) / gridDim.x;
    int n0 = blockIdx.x * per;
    int n1 = min(n, n0 + per);
    float acc = 0.f;
    int curg = -1;
    for (int i = n0 + rowl; i < n1; i += 8) {
        int g = batch[i];
        if (g != curg) {
            if (curg >= 0) atomicAdd(&pool[curg * 32 + h], acc);
            acc = 0.f;
            curg = g;
        }
        acc += x3[i * 32 + h];
    }
    if (curg >= 0) atomicAdd(&pool[curg * 32 + h], acc);
}

__global__ __launch_bounds__(64) void head_kernel(const float* __restrict__ pool,
                                                  const int* __restrict__ batch,
                                                  const float* __restrict__ Wlin,
                                                  const float* __restrict__ blin,
                                                  float* out, int n, int G) {
    int g = threadIdx.x;
    if (g >= G) return;
    float s = 0.f;
#pragma unroll
    for (int k = 0; k < 32; k++) s = fmaf(pool[g * 32 + k], Wlin[k], s);
    // node count of graph g via binary search on sorted batch
    int lo = 0, hi = n;
    while (lo < hi) {
        int m = (lo + hi) >> 1;
        if (batch[m] < g) lo = m + 1; else hi = m;
    }
    int start = lo;
    lo = 0; hi = n;
    while (lo < hi) {
        int m = (lo + hi) >> 1;
        if (batch[m] < g + 1) lo = m + 1; else hi = m;
    }
    float c = fmaxf((float)(lo - start), 1.f);
    out[g] = s / c + blin[0];
}

extern "C" void kernel_launch(void* const* d_in, const int* in_sizes, int n_in,
                              void* d_out, int out_size, void* d_ws, size_t ws_size,
                              hipStream_t stream) {
    const float* x    = (const float*)d_in[0];
    const float* ea0  = (const float*)d_in[1];
    const int* ei     = (const int*)d_in[2];
    const int* batch  = (const int*)d_in[3];
    const float* Wn[3] = {(const float*)d_in[4], (const float*)d_in[9],  (const float*)d_in[14]};
    const float* bn[3] = {(const float*)d_in[5], (const float*)d_in[10], (const float*)d_in[15]};
    const float* We[3] = {(const float*)d_in[6], (const float*)d_in[11], (const float*)d_in[16]};
    const float* be[3] = {(const float*)d_in[7], (const float*)d_in[12], (const float*)d_in[17]};
    const float* att[3]= {(const float*)d_in[8], (const float*)d_in[13], (const float*)d_in[18]};
    const float* Wlin = (const float*)d_in[19];
    const float* blin = (const float*)d_in[20];
    float* out = (float*)d_out;

    const int N = in_sizes[0] / 16;
    const int E = in_sizes[1] / 8;
    const int G = out_size;
    (void)n_in; (void)ws_size;

    const int* srcp = ei;
    const int* dstp = ei + E;

    // workspace carve (256B aligned)
    char* base = (char*)d_ws;
    size_t off = 0;
    auto carve = [&](size_t bytes) -> void* {
        void* p = base + off;
        off = (off + bytes + 255) & ~(size_t)255;
        return p;
    };
    float* xnA   = (float*)carve((size_t)N * 32 * 4);
    float* xnB   = (float*)carve((size_t)N * 32 * 4);
    float* ai    = (float*)carve((size_t)N * 4);
    float* aj    = (float*)carve((size_t)N * 4);
    float* ea    = (float*)carve((size_t)E * 8 * 4);
    float* ae    = (float*)carve((size_t)E * 4);
    int* cnt     = (int*)carve((size_t)N * 4);
    int* rowptr  = (int*)carve((size_t)(N + 1) * 4);
    int* cursor  = (int*)carve((size_t)N * 4);
    int* eid     = (int*)carve((size_t)E * 4);
    int* esrc    = (int*)carve((size_t)E * 4);
    float* pool  = (float*)carve((size_t)G * 32 * 4);

    int ebks = (E + 255) / 256;
    int nhbks = (N * 32 + 255) / 256;
    int aggbks = (N + 3) / 4;  // 4 waves / block, 1 wave / node

    // CSR build (graph is static across layers)
    zero_kernel<<<(N + 255) / 256, 256, 0, stream>>>(cnt, pool, N, G * 32);
    hist_kernel<<<ebks, 256, 0, stream>>>(dstp, cnt, E);
    scan_kernel<<<1, 1024, 0, stream>>>(cnt, rowptr, cursor, N);
    scatter_kernel<<<ebks, 256, 0, stream>>>(srcp, dstp, cursor, eid, esrc, E);

    // layer 1 (input x is [N,16]; relu folded into aggregate epilogue)
    node_linear<16><<<nhbks, 256, 0, stream>>>(x, Wn[0], bn[0], att[0], xnA, ai, aj, N);
    edge_linear<<<ebks, 256, 0, stream>>>(ea0, We[0], be[0], att[0] + 64, ea, ae, E, 1);
    gat_aggregate<<<aggbks, 256, 0, stream>>>(xnA, ai, aj, ae, rowptr, eid, esrc, xnB, N, 1);

    // layer 2 (edge transform in-place on ea)
    node_linear<32><<<nhbks, 256, 0, stream>>>(xnB, Wn[1], bn[1], att[1], xnA, ai, aj, N);
    edge_linear<<<ebks, 256, 0, stream>>>(ea, We[1], be[1], att[1] + 64, ea, ae, E, 1);
    gat_aggregate<<<aggbks, 256, 0, stream>>>(xnA, ai, aj, ae, rowptr, eid, esrc, xnB, N, 1);

    // layer 3 (ea3 only needed via ae; no relu on x3)
    node_linear<32><<<nhbks, 256, 0, stream>>>(xnB, Wn[2], bn[2], att[2], xnA, ai, aj, N);
    edge_linear<<<ebks, 256, 0, stream>>>(ea, We[2], be[2], att[2] + 64, nullptr, ae, E, 0);
    gat_aggregate<<<aggbks, 256, 0, stream>>>(xnA, ai, aj, ae, rowptr, eid, esrc, xnB, N, 0);

    // mean pool + head
    pool_kernel<<<128, 256, 0, stream>>>(xnB, batch, pool, N);
    head_kernel<<<1, 64, 0, stream>>>(pool, batch, Wlin, blin, out, N, G);
}

// Round 2
// 741.432 us; speedup vs baseline: 1.0503x; 1.0503x over previous
//
#include <hip/hip_runtime.h>
#include <math.h>

// ---------------------------------------------------------------------------
// WEGAT: 3x edge-weighted GAT conv + mean pool + linear head.
// Decomposition: logit[e] = ai[dst] + aj[src] + ae[e]  (att dot split).
// CSR-by-dst built per launch -> atomic-free softmax + aggregation,
// one wave (64 lanes) per destination node.
// R1: packed int2 CSR payload (halve scatter write amplification);
//     fused edge chain (ea2/ea3 never hit HBM, only ae1/ae2/ae3 stored).
// ---------------------------------------------------------------------------

__global__ __launch_bounds__(256) void hist_kernel(const int* __restrict__ dst, int* cnt, int E) {
    int e = blockIdx.x * blockDim.x + threadIdx.x;
    if (e < E) atomicAdd(&cnt[dst[e]], 1);
}

// Single-block exclusive scan over N counts (N ~ 50000). 1024 threads,
// each handles a contiguous chunk; Hillis-Steele over the 1024 chunk sums.
__global__ __launch_bounds__(1024) void scan_kernel(const int* __restrict__ cnt,
                                                    int* rowptr, int* cursor, int n) {
    __shared__ int sums[1024];
    int t = threadIdx.x;
    int CH = (n + 1023) >> 10;
    int s0 = t * CH;
    int s1 = min(n, s0 + CH);
    int local = 0;
    for (int i = s0; i < s1; i++) local += cnt[i];
    sums[t] = local;
    __syncthreads();
    for (int off = 1; off < 1024; off <<= 1) {
        int v = (t >= off) ? sums[t - off] : 0;
        __syncthreads();
        sums[t] += v;
        __syncthreads();
    }
    int run = (t == 0) ? 0 : sums[t - 1];
    for (int i = s0; i < s1; i++) {
        rowptr[i] = run;
        cursor[i] = run;
        run += cnt[i];
    }
    if (t == 1023) rowptr[n] = sums[1023];
}

// pack[pos] = {src, e} — single 8B store per edge (half the dirty lines of
// two separate 4B scatters).
__global__ __launch_bounds__(256) void scatter_kernel(const int* __restrict__ src,
                                                      const int* __restrict__ dst,
                                                      int* cursor, int2* __restrict__ pack, int E) {
    int e = blockIdx.x * blockDim.x + threadIdx.x;
    if (e >= E) return;
    int d = dst[e];
    int pos = atomicAdd(&cursor[d], 1);
    pack[pos] = make_int2(src[e], e);
}

// xn = xin @ Wn + bn ; ai = xn . att[0:32] ; aj = xn . att[32:64]
// 32 lanes per node (h = lane&31).
template <int IN>
__global__ __launch_bounds__(256) void node_linear(const float* __restrict__ xin,
                                                   const float* __restrict__ Wn,
                                                   const float* __restrict__ bn,
                                                   const float* __restrict__ att,
                                                   float* __restrict__ xn,
                                                   float* __restrict__ ai,
                                                   float* __restrict__ aj, int n) {
    int t = blockIdx.x * blockDim.x + threadIdx.x;
    int node = t >> 5;
    int h = t & 31;
    if (node >= n) return;
    float acc = bn[h];
#pragma unroll
    for (int k = 0; k < IN; k++) {
        acc = fmaf(xin[node * IN + k], Wn[k * 32 + h], acc);
    }
    xn[node * 32 + h] = acc;
    float pi = acc * att[h];
    float pj = acc * att[32 + h];
#pragma unroll
    for (int off = 16; off > 0; off >>= 1) {
        pi += __shfl_xor(pi, off);
        pj += __shfl_xor(pj, off);
    }
    if (h == 0) {
        ai[node] = pi;
        aj[node] = pj;
    }
}

// Fused edge-feature chain: ea0 -> ea2 -> ea3 entirely in registers.
// Only the three attention scalars ae1/ae2/ae3 are stored (19 MB vs 330 MB
// of traffic for three separate passes materializing ea2/ea3).
__global__ __launch_bounds__(256) void edge_chain(
    const float* __restrict__ ein,
    const float* __restrict__ We1, const float* __restrict__ be1, const float* __restrict__ a1,
    const float* __restrict__ We2, const float* __restrict__ be2, const float* __restrict__ a2,
    const float* __restrict__ We3, const float* __restrict__ be3, const float* __restrict__ a3,
    float* __restrict__ ae1, float* __restrict__ ae2, float* __restrict__ ae3, int E) {
    int e = blockIdx.x * blockDim.x + threadIdx.x;
    if (e >= E) return;
    const float4* p = (const float4*)(ein + (size_t)e * 8);
    float4 x0 = p[0], x1 = p[1];
    float v[8] = {x0.x, x0.y, x0.z, x0.w, x1.x, x1.y, x1.z, x1.w};
    float t[8], u[8];
    float d1 = 0.f, d2 = 0.f, d3 = 0.f;
#pragma unroll
    for (int j = 0; j < 8; j++) {
        float a = be1[j];
#pragma unroll
        for (int k = 0; k < 8; k++) a = fmaf(v[k], We1[k * 8 + j], a);
        t[j] = a;
        d1 = fmaf(a, a1[j], d1);
    }
#pragma unroll
    for (int j = 0; j < 8; j++) {
        float a = be2[j];
#pragma unroll
        for (int k = 0; k < 8; k++) a = fmaf(t[k], We2[k * 8 + j], a);
        u[j] = a;
        d2 = fmaf(a, a2[j], d2);
    }
#pragma unroll
    for (int j = 0; j < 8; j++) {
        float a = be3[j];
#pragma unroll
        for (int k = 0; k < 8; k++) a = fmaf(u[k], We3[k * 8 + j], a);
        d3 = fmaf(a, a3[j], d3);
    }
    ae1[e] = d1;
    ae2[e] = d2;
    ae3[e] = d3;
}

// One wave per dst node. Phase 1: wave-max of leaky_relu(logit).
// Phase 2: per-lane exp, then 2 half-waves (h = lane&31) accumulate
// sum_e p_e * xn[src_e][h] via shuffle broadcast. Normalize, optional relu.
__global__ __launch_bounds__(256) void gat_aggregate(const float* __restrict__ xn,
                                                     const float* __restrict__ ai,
                                                     const float* __restrict__ aj,
                                                     const float* __restrict__ ae,
                                                     const int* __restrict__ rowptr,
                                                     const int2* __restrict__ pack,
                                                     float* __restrict__ xout,
                                                     int n, int relu_out) {
    int wave = (blockIdx.x * blockDim.x + threadIdx.x) >> 6;
    int lane = threadIdx.x & 63;
    if (wave >= n) return;
    int node = wave;
    int row = rowptr[node];
    int deg = rowptr[node + 1] - row;
    int h = lane & 31;
    if (deg == 0) {
        if (lane < 32) xout[node * 32 + h] = 0.f;
        return;
    }
    float a_i = ai[node];
    const int2* pk = pack + row;

    // phase 1: max logit
    float mx = -INFINITY;
    for (int k = lane; k < deg; k += 64) {
        int2 q = pk[k];
        float lg = a_i + aj[q.x] + ae[q.y];
        lg = (lg >= 0.f) ? lg : 0.2f * lg;
        mx = fmaxf(mx, lg);
    }
#pragma unroll
    for (int off = 32; off > 0; off >>= 1) mx = fmaxf(mx, __shfl_xor(mx, off));

    // phase 2: exp + weighted gather-accumulate
    float acc = 0.f, psum = 0.f;
    int half = lane >> 5;
    for (int base = 0; base < deg; base += 64) {
        int k = base + lane;
        float p = 0.f;
        int s = 0;
        if (k < deg) {
            int2 q = pk[k];
            s = q.x;
            float lg = a_i + aj[s] + ae[q.y];
            lg = (lg >= 0.f) ? lg : 0.2f * lg;
            p = expf(lg - mx);
        }
        psum += p;
        int csize = min(64, deg - base);
        for (int j = half; j < csize; j += 2) {
            float pj = __shfl(p, j);
            int sj = __shfl(s, j);
            acc = fmaf(pj, xn[sj * 32 + h], acc);
        }
    }
#pragma unroll
    for (int off = 32; off > 0; off >>= 1) psum += __shfl_xor(psum, off);
    acc += __shfl_xor(acc, 32);

    float o = acc / (psum + 1e-16f);
    if (relu_out) o = fmaxf(o, 0.f);
    if (lane < 32) xout[node * 32 + h] = o;
}

// Sorted-batch running-flush partial pooling: few atomics per thread.
__global__ __launch_bounds__(256) void pool_kernel(const float* __restrict__ x3,
                                                   const int* __restrict__ batch,
                                                   float* pool, int n) {
    int h = threadIdx.x & 31;
    int rowl = threadIdx.x >> 5;  // 0..7
    int per = (n + gridDim.x - 1) / gridDim.x;
    int n0 = blockIdx.x * per;
    int n1 = min(n, n0 + per);
    float acc = 0.f;
    int curg = -1;
    for (int i = n0 + rowl; i < n1; i += 8) {
        int g = batch[i];
        if (g != curg) {
            if (curg >= 0) atomicAdd(&pool[curg * 32 + h], acc);
            acc = 0.f;
            curg = g;
        }
        acc += x3[i * 32 + h];
    }
    if (curg >= 0) atomicAdd(&pool[curg * 32 + h], acc);
}

__global__ __launch_bounds__(64) void head_kernel(const float* __restrict__ pool,
                                                  const int* __restrict__ batch,
                                                  const float* __restrict__ Wlin,
                                                  const float* __restrict__ blin,
                                                  float* out, int n, int G) {
    int g = threadIdx.x;
    if (g >= G) return;
    float s = 0.f;
#pragma unroll
    for (int k = 0; k < 32; k++) s = fmaf(pool[g * 32 + k], Wlin[k], s);
    // node count of graph g via binary search on sorted batch
    int lo = 0, hi = n;
    while (lo < hi) {
        int m = (lo + hi) >> 1;
        if (batch[m] < g) lo = m + 1; else hi = m;
    }
    int start = lo;
    lo = 0; hi = n;
    while (lo < hi) {
        int m = (lo + hi) >> 1;
        if (batch[m] < g + 1) lo = m + 1; else hi = m;
    }
    float c = fmaxf((float)(lo - start), 1.f);
    out[g] = s / c + blin[0];
}

extern "C" void kernel_launch(void* const* d_in, const int* in_sizes, int n_in,
                              void* d_out, int out_size, void* d_ws, size_t ws_size,
                              hipStream_t stream) {
    const float* x    = (const float*)d_in[0];
    const float* ea0  = (const float*)d_in[1];
    const int* ei     = (const int*)d_in[2];
    const int* batch  = (const int*)d_in[3];
    const float* Wn[3] = {(const float*)d_in[4], (const float*)d_in[9],  (const float*)d_in[14]};
    const float* bn[3] = {(const float*)d_in[5], (const float*)d_in[10], (const float*)d_in[15]};
    const float* We[3] = {(const float*)d_in[6], (const float*)d_in[11], (const float*)d_in[16]};
    const float* be[3] = {(const float*)d_in[7], (const float*)d_in[12], (const float*)d_in[17]};
    const float* att[3]= {(const float*)d_in[8], (const float*)d_in[13], (const float*)d_in[18]};
    const float* Wlin = (const float*)d_in[19];
    const float* blin = (const float*)d_in[20];
    float* out = (float*)d_out;

    const int N = in_sizes[0] / 16;
    const int E = in_sizes[1] / 8;
    const int G = out_size;
    (void)n_in; (void)ws_size;

    const int* srcp = ei;
    const int* dstp = ei + E;

    // workspace carve (256B aligned)
    char* base = (char*)d_ws;
    size_t off = 0;
    auto carve = [&](size_t bytes) -> void* {
        void* p = base + off;
        off = (off + bytes + 255) & ~(size_t)255;
        return p;
    };
    float* xnA   = (float*)carve((size_t)N * 32 * 4);
    float* xnB   = (float*)carve((size_t)N * 32 * 4);
    float* ai    = (float*)carve((size_t)N * 4);
    float* aj    = (float*)carve((size_t)N * 4);
    float* ae1   = (float*)carve((size_t)E * 4);
    float* ae2   = (float*)carve((size_t)E * 4);
    float* ae3   = (float*)carve((size_t)E * 4);
    int* cnt     = (int*)carve((size_t)N * 4);
    int* rowptr  = (int*)carve((size_t)(N + 1) * 4);
    int* cursor  = (int*)carve((size_t)N * 4);
    int2* pack   = (int2*)carve((size_t)E * 8);
    float* pool  = (float*)carve((size_t)G * 32 * 4);

    int ebks = (E + 255) / 256;
    int nhbks = (N * 32 + 255) / 256;
    int aggbks = (N + 3) / 4;  // 4 waves / block, 1 wave / node

    // CSR build (graph is static across layers)
    hipMemsetAsync(cnt, 0, (size_t)N * 4, stream);
    hipMemsetAsync(pool, 0, (size_t)G * 32 * 4, stream);
    hist_kernel<<<ebks, 256, 0, stream>>>(dstp, cnt, E);
    scan_kernel<<<1, 1024, 0, stream>>>(cnt, rowptr, cursor, N);
    scatter_kernel<<<ebks, 256, 0, stream>>>(srcp, dstp, cursor, pack, E);

    // fused edge-feature chain (independent of node features)
    edge_chain<<<ebks, 256, 0, stream>>>(ea0,
                                         We[0], be[0], att[0] + 64,
                                         We[1], be[1], att[1] + 64,
                                         We[2], be[2], att[2] + 64,
                                         ae1, ae2, ae3, E);

    // layer 1 (input x is [N,16]; relu folded into aggregate epilogue)
    node_linear<16><<<nhbks, 256, 0, stream>>>(x, Wn[0], bn[0], att[0], xnA, ai, aj, N);
    gat_aggregate<<<aggbks, 256, 0, stream>>>(xnA, ai, aj, ae1, rowptr, pack, xnB, N, 1);

    // layer 2
    node_linear<32><<<nhbks, 256, 0, stream>>>(xnB, Wn[1], bn[1], att[1], xnA, ai, aj, N);
    gat_aggregate<<<aggbks, 256, 0, stream>>>(xnA, ai, aj, ae2, rowptr, pack, xnB, N, 1);

    // layer 3 (no relu on x3)
    node_linear<32><<<nhbks, 256, 0, stream>>>(xnB, Wn[2], bn[2], att[2], xnA, ai, aj, N);
    gat_aggregate<<<aggbks, 256, 0, stream>>>(xnA, ai, aj, ae3, rowptr, pack, xnB, N, 0);

    // mean pool + head
    pool_kernel<<<128, 256, 0, stream>>>(xnB, batch, pool, N);
    head_kernel<<<1, 64, 0, stream>>>(pool, batch, Wlin, blin, out, N, G);
}